// Round 1
// 65.372 us; speedup vs baseline: 1.0299x; 1.0299x over previous
//
#include <hip/hip_runtime.h>

// one_layer_net: 130-step scan over a 9x3 LUT-triangle network.
// V2: K-form coefficients (3-fma inner chain), constant-input folding
// (removes the cndmask + lanes 27/28 special-casing), full unroll of the
// serial loop (LDS reads become base+imm-offset, no loop overhead).
//
// Inner step per lane:  new = fma(gB, fma(gA,K3,K2), fma(gA,K1,K0))
// where (K3,K2,K1,K0) are precomputed per (step,lut) in phase 1:
//   K3 = 0.25*((w3-w2)-(w1-w0))   [gA*gB term]
//   K2 = 0.25*((w2+w3)-(w0+w1))   [gB term]
//   K1 = 0.25*((w1-w0)+(w3-w2))   [gA term]
//   K0 = 0.25*(w0+w1+w2+w3)       [const]
// Lanes whose gB is a network input (srcB==27/28) get it folded:
//   K0 += K2*c; K1 += K3*c; K2 = K3 = 0   -> no gather ever targets lane>=27.

#define STEPS 130
#define NLUT  27   // 9 triangles x 3 LUTs

// Source wiring (indices into flat[29] = [prev.flatten(27), a, b])
__device__ __constant__ int c_idx0[9] = {3, 0, 6, 12, 9, 15, 18, 6, 15};
__device__ __constant__ int c_idx1[9] = {1, 7, 4, 19, 16, 13, 10, 22, 25};
__device__ __constant__ int c_idx2[9] = {17, 5, 11, 8, 28, 2, 27, 23, 26};

__global__ __launch_bounds__(1024)
void one_layer_net_kernel(const float* __restrict__ x,
                          const float* __restrict__ weights,
                          const float* __restrict__ noise,
                          float* __restrict__ out) {
    __shared__ float4 tbl[STEPS * NLUT];   // 130*27*16 = 56160 B LDS

    const int tid = threadIdx.x;
    const float a = x[0];
    const float b = x[1];

    // ---- Phase 1: parallel precompute of K-form coefficients ----
    // w' = w + |1 - |w|| * n * 0.125
    const float4* __restrict__ w4 = (const float4*)weights; // [27]
    const float4* __restrict__ n4 = (const float4*)noise;   // [130*27]
    for (int i = tid; i < STEPS * NLUT; i += 1024) {
        const int l = i % NLUT;
        float4 w = w4[l];
        float4 n = n4[i];
        float w0 = fmaf(fabsf(1.0f - fabsf(w.x)) * n.x, 0.125f, w.x);
        float w1 = fmaf(fabsf(1.0f - fabsf(w.y)) * n.y, 0.125f, w.y);
        float w2 = fmaf(fabsf(1.0f - fabsf(w.z)) * n.z, 0.125f, w.z);
        float w3 = fmaf(fabsf(1.0f - fabsf(w.w)) * n.w, 0.125f, w.w);
        float d0 = w1 - w0, s0 = w0 + w1;
        float d1 = w3 - w2, s1 = w2 + w3;
        float K3 = 0.25f * (d1 - d0);
        float K2 = 0.25f * (s1 - s0);
        float K1 = 0.25f * (d0 + d1);
        float K0 = 0.25f * (s0 + s1);
        // fold constant gB inputs: lanes 12,13 read b (flat[28]); 18,19 read a (flat[27])
        if (l == 12 || l == 13) {
            K0 = fmaf(K2, b, K0); K1 = fmaf(K3, b, K1); K2 = 0.0f; K3 = 0.0f;
        }
        if (l == 18 || l == 19) {
            K0 = fmaf(K2, a, K0); K1 = fmaf(K3, a, K1); K2 = 0.0f; K3 = 0.0f;
        }
        tbl[i] = make_float4(K3, K2, K1, K0);
    }
    __syncthreads();

    // ---- Phase 2: serial 130-step loop on wave 0 only ----
    if (tid >= 64) return;

    const int l  = tid;
    const int lc = (l < NLUT) ? l : (NLUT - 1); // lanes 27..63 mirror lane 26
    const int t  = lc / 3;
    const int j  = lc % 3;
    // LUT0(x1,x2): selA=x1 selB=x2 | LUT1(x0,x2): selA=x0 selB=x2
    // LUT2(x0,x1): selA=x0 selB=x1
    int srcA = (j == 0) ? c_idx1[t] : c_idx0[t];
    int srcB = (j == 2) ? c_idx1[t] : c_idx2[t];
    if (srcB >= NLUT) srcB = 0;   // folded lanes: gB multiplied by 0, source irrelevant
    const int bpA = srcA << 2;    // ds_bpermute byte index
    const int bpB = srcB << 2;

    // All lanes init -1; lanes >=27 compute lane-26 duplicates (finite, never read).
    float state = -1.0f;

    const float4* __restrict__ row = &tbl[lc];
    float4 k = row[0];
    #pragma unroll
    for (int s = 0; s < STEPS; ++s) {
        const float4 kc = k;
        if (s + 1 < STEPS) k = row[(s + 1) * NLUT];   // imm-offset prefetch
        const int si = __float_as_int(state);
        const float gA = __int_as_float(__builtin_amdgcn_ds_bpermute(bpA, si));
        const float gB = __int_as_float(__builtin_amdgcn_ds_bpermute(bpB, si));
        const float t0 = fmaf(gA, kc.x, kc.y);   // K3*gA + K2
        const float t1 = fmaf(gA, kc.z, kc.w);   // K1*gA + K0
        state = fmaf(gB, t0, t1);                // unconditional update, no cndmask
    }

    // outputs: final[0,1] -> lane 1, final[1,2] -> lane 5, final[7,2] -> lane 23
    if (l == 1)  out[0] = state;
    if (l == 5)  out[1] = state;
    if (l == 23) out[2] = state;
}

extern "C" void kernel_launch(void* const* d_in, const int* in_sizes, int n_in,
                              void* d_out, int out_size, void* d_ws, size_t ws_size,
                              hipStream_t stream) {
    const float* x       = (const float*)d_in[0]; // [2]
    const float* weights = (const float*)d_in[1]; // [9,3,4]
    const float* noise   = (const float*)d_in[2]; // [130,9,3,4]
    float* out = (float*)d_out;                   // [3] float32
    one_layer_net_kernel<<<1, 1024, 0, stream>>>(x, weights, noise, out);
}